// Round 1
// baseline (120.158 us; speedup 1.0000x reference)
//
#include <hip/hip_runtime.h>

// AttentionHead: B=4, S=4096, D=64, fp32 in/out.
// Flash attention, 32x32x16 bf16 MFMA with hi/lo (Dekker) split for fp32-grade
// accuracy. 3 kernels: prep (split K / split+transpose V into ws), attn
// (flash loop, KV-split x4, partials to ws), merge (combine partials).

#define BATCH 4
#define SEQ   4096
#define DIM   64
#define KVB   32
#define NSPLIT 4
#define SPLITLEN (SEQ / NSPLIT)   // 1024
#define NIT   (SPLITLEN / KVB)    // 32
#define QSCALE 0.18033688011112042f  // (1/sqrt(64)) * log2(e); all exps are exp2

typedef float f32x16 __attribute__((ext_vector_type(16)));
typedef unsigned short u16x8 __attribute__((ext_vector_type(8)));
typedef unsigned int   u32x4 __attribute__((ext_vector_type(4)));

#define MFMA32(a, b, c) __builtin_amdgcn_mfma_f32_32x32x16_bf16((a), (b), (c), 0, 0, 0)

__device__ __forceinline__ unsigned short f2bf(float x) {
  unsigned int u = __float_as_uint(x);
  return (unsigned short)((u + 0x7fffu + ((u >> 16) & 1u)) >> 16);   // RNE
}
__device__ __forceinline__ float bf2f(unsigned short h) {
  return __uint_as_float(((unsigned int)h) << 16);
}

// ---------------- prep: K -> Khi/Klo [B][S][D]; V -> VThi/VTlo [B][D][S] ----
__global__ __launch_bounds__(256) void prep_kernel(
    const float* __restrict__ K, const float* __restrict__ V,
    unsigned short* __restrict__ Khi, unsigned short* __restrict__ Klo,
    unsigned short* __restrict__ VThi, unsigned short* __restrict__ VTlo) {
  const int N = BATCH * SEQ * DIM;  // 1048576
  for (int i = blockIdx.x * blockDim.x + threadIdx.x; i < 2 * N;
       i += gridDim.x * blockDim.x) {
    if (i < N) {
      float x = K[i];
      unsigned short h = f2bf(x);
      Khi[i] = h;
      Klo[i] = f2bf(x - bf2f(h));
    } else {
      int j = i - N;
      int b = j >> 18;          // DIM*SEQ = 262144
      int r = j & 0x3ffff;
      int d = r >> 12;          // SEQ = 4096
      int s = r & 0xfff;
      float x = V[(b << 18) + (s << 6) + d];
      unsigned short h = f2bf(x);
      VThi[j] = h;
      VTlo[j] = f2bf(x - bf2f(h));
    }
  }
}

// ---------------- attention main kernel ------------------------------------
// Grid 512 = 4 batch * 4 kvsplit * 32 qblocks(128q). WG = 4 waves, 32 q/wave.
__global__ __launch_bounds__(256) void attn_kernel(
    const float* __restrict__ Q,
    const unsigned short* __restrict__ Khi, const unsigned short* __restrict__ Klo,
    const unsigned short* __restrict__ VThi, const unsigned short* __restrict__ VTlo,
    float* __restrict__ Opart, float* __restrict__ Mpart, float* __restrict__ Lpart) {

  // LDS: K tile [buf][hi/lo][32 keys][64 d], V^T tile [buf][hi/lo][64 d][32 k]
  __shared__ __align__(16) unsigned short kt[2][2][KVB][DIM];   // 16 KB
  __shared__ __align__(16) unsigned short vt[2][2][DIM][KVB];   // 16 KB
  __shared__ __align__(16) unsigned int   pbuf[4][32][32];      // 16 KB (per-wave P)

  // XCD-contiguous block swizzle: each XCD gets 64 consecutive logical blocks
  const int raw = blockIdx.x;
  const int bid = ((raw & 7) << 6) | (raw >> 3);
  const int b     = bid >> 7;        // batch
  const int rem   = bid & 127;
  const int split = rem >> 5;        // kv split 0..3
  const int qblk  = rem & 31;        // 128-query block

  const int tid  = threadIdx.x;
  const int wave = tid >> 6;
  const int lane = tid & 63;
  const int l5   = lane & 31;
  const int b5   = lane >> 5;

  const int qrow0 = qblk * 128 + wave * 32;
  const int kv0   = split * SPLITLEN;

  // ---- Q fragments: q row = l5; frag[ch] elem j <-> d = 16*ch + 8*b5 + j ----
  u16x8 qh[4], qlo[4];
  {
    const float* qp = Q + ((long)b * SEQ + qrow0 + l5) * DIM;
    #pragma unroll
    for (int ch = 0; ch < 4; ++ch) {
      const float* p = qp + ch * 16 + b5 * 8;
      float4 x0 = *(const float4*)(p);
      float4 x1 = *(const float4*)(p + 4);
      float vv[8] = {x0.x, x0.y, x0.z, x0.w, x1.x, x1.y, x1.z, x1.w};
      #pragma unroll
      for (int j = 0; j < 8; ++j) {
        float sv = vv[j] * QSCALE;
        unsigned short h = f2bf(sv);
        qh[ch][j]  = h;
        qlo[ch][j] = f2bf(sv - bf2f(h));
      }
    }
  }

  // wave -> which array it stages
  const unsigned short* sK = (wave == 0) ? Khi : Klo;
  const unsigned short* sV = (wave == 2) ? VThi : VTlo;

  // global source is pre-swizzled so the LDS write is linear (rule #21 analog)
  auto stage_load = [&](int kb, float4* stg) {
    if (wave < 2) {
      #pragma unroll
      for (int L = 0; L < 4; ++L) {
        int key = L * 8 + (lane >> 3);
        int cb  = (lane & 7) ^ (lane >> 3);      // K swizzle: blk ^ (key&7)
        stg[L] = *(const float4*)(sK + ((long)b * SEQ + kb + key) * DIM + cb * 8);
      }
    } else {
      #pragma unroll
      for (int L = 0; L < 4; ++L) {
        int d  = L * 16 + (lane >> 2);
        int cb = (lane & 3) ^ ((lane >> 3) & 3); // V swizzle: blk ^ ((d>>1)&3)
        stg[L] = *(const float4*)(sV + (long)b * DIM * SEQ + (long)d * SEQ + kb + cb * 8);
      }
    }
  };
  auto stage_write = [&](int buf, const float4* stg) {
    unsigned short* dst = (wave < 2) ? &kt[buf][wave][0][0] : &vt[buf][wave - 2][0][0];
    #pragma unroll
    for (int L = 0; L < 4; ++L)
      *(float4*)(dst + L * 512 + lane * 8) = stg[L];
  };

  // prologue: stage tile 0 into buffer 0
  {
    float4 stg[4];
    stage_load(kv0, stg);
    stage_write(0, stg);
  }
  __syncthreads();

  f32x16 O0 = {0,0,0,0,0,0,0,0,0,0,0,0,0,0,0,0};
  f32x16 O1 = {0,0,0,0,0,0,0,0,0,0,0,0,0,0,0,0};
  float m = -INFINITY, lsum = 0.0f;

  for (int t = 0; t < NIT; ++t) {
    const int cur = t & 1;
    const bool more = (t + 1 < NIT);
    float4 stg[4];
    if (more) stage_load(kv0 + (t + 1) * KVB, stg);   // issue early (T14)

    const unsigned short* ktc = &kt[cur][0][0][0];    // hi; lo at +2048
    const unsigned short* vtc = &vt[cur][0][0][0];

    // ---- QK^T swapped: sacc = S^T, row=key=(r&3)+8*(r>>2)+4*b5, col=q=l5 ----
    f32x16 sacc = {0,0,0,0,0,0,0,0,0,0,0,0,0,0,0,0};
    #pragma unroll
    for (int ch = 0; ch < 4; ++ch) {
      int off = l5 * DIM + ((((ch << 1) | b5) ^ (l5 & 7)) << 3);
      u16x8 kh = *(const u16x8*)(ktc + off);
      u16x8 kl = *(const u16x8*)(ktc + 2048 + off);
      sacc = MFMA32(kh, qh[ch],  sacc);
      sacc = MFMA32(kl, qh[ch],  sacc);
      sacc = MFMA32(kh, qlo[ch], sacc);
    }

    // ---- online softmax (per lane: one q, 16 of 32 keys; partner = lane^32) -
    float smax = sacc[0];
    #pragma unroll
    for (int r = 1; r < 16; ++r) smax = fmaxf(smax, sacc[r]);
    smax = fmaxf(smax, __shfl_xor(smax, 32));
    float mn = fmaxf(m, smax);
    float fs = exp2f(m - mn);
    m = mn;
    float p[16];
    float ps = 0.0f;
    #pragma unroll
    for (int r = 0; r < 16; ++r) { p[r] = exp2f(sacc[r] - mn); ps += p[r]; }
    ps += __shfl_xor(ps, 32);
    lsum = lsum * fs + ps;
    #pragma unroll
    for (int r = 0; r < 16; ++r) { O0[r] *= fs; O1[r] *= fs; }

    // ---- P (hi|lo packed u32) -> per-wave LDS, swizzled quads --------------
    #pragma unroll
    for (int g = 0; g < 4; ++g) {
      unsigned int w0_, w1_, w2_, w3_;
      {
        float pv; unsigned short ph, pl;
        pv = p[g*4+0]; ph = f2bf(pv); pl = f2bf(pv - bf2f(ph)); w0_ = (unsigned)ph | ((unsigned)pl << 16);
        pv = p[g*4+1]; ph = f2bf(pv); pl = f2bf(pv - bf2f(ph)); w1_ = (unsigned)ph | ((unsigned)pl << 16);
        pv = p[g*4+2]; ph = f2bf(pv); pl = f2bf(pv - bf2f(ph)); w2_ = (unsigned)ph | ((unsigned)pl << 16);
        pv = p[g*4+3]; ph = f2bf(pv); pl = f2bf(pv - bf2f(ph)); w3_ = (unsigned)ph | ((unsigned)pl << 16);
      }
      int qd = (g << 1) | b5;                       // quad of keys 8g+4*b5 .. +3
      u32x4 wq = {w0_, w1_, w2_, w3_};
      *(u32x4*)&pbuf[wave][l5][(qd ^ (l5 & 7)) << 2] = wq;
    }

    // ---- read P^T B-fragments back (keys 16*kc + 8*b5 + j for q=l5) --------
    u16x8 pbh[2], pbl[2];
    #pragma unroll
    for (int kc = 0; kc < 2; ++kc) {
      int qd0 = (kc << 2) | (b5 << 1);
      u32x4 r0 = *(const u32x4*)&pbuf[wave][l5][((qd0)     ^ (l5 & 7)) << 2];
      u32x4 r1 = *(const u32x4*)&pbuf[wave][l5][((qd0 + 1) ^ (l5 & 7)) << 2];
      u32x4 hw = { (r0[0] & 0xffffu) | (r0[1] << 16),
                   (r0[2] & 0xffffu) | (r0[3] << 16),
                   (r1[0] & 0xffffu) | (r1[1] << 16),
                   (r1[2] & 0xffffu) | (r1[3] << 16) };
      u32x4 lw = { (r0[0] >> 16) | (r0[1] & 0xffff0000u),
                   (r0[2] >> 16) | (r0[3] & 0xffff0000u),
                   (r1[0] >> 16) | (r1[1] & 0xffff0000u),
                   (r1[2] >> 16) | (r1[3] & 0xffff0000u) };
      pbh[kc] = __builtin_bit_cast(u16x8, hw);
      pbl[kc] = __builtin_bit_cast(u16x8, lw);
    }

    // ---- PV: O^T[d][q] += V^T * P^T (3 split terms) ------------------------
    #pragma unroll
    for (int mt = 0; mt < 2; ++mt) {
      f32x16 Oa = mt ? O1 : O0;
      int d = mt * 32 + l5;
      #pragma unroll
      for (int kc = 0; kc < 2; ++kc) {
        int off = d * 32 + ((((kc << 1) | b5) ^ ((d >> 1) & 3)) << 3);
        u16x8 vh = *(const u16x8*)(vtc + off);
        u16x8 vl = *(const u16x8*)(vtc + 2048 + off);
        Oa = MFMA32(vh, pbh[kc], Oa);
        Oa = MFMA32(vh, pbl[kc], Oa);
        Oa = MFMA32(vl, pbh[kc], Oa);
      }
      if (mt) O1 = Oa; else O0 = Oa;
    }

    if (more) stage_write(cur ^ 1, stg);            // write late (T14)
    __syncthreads();
  }

  // ---- epilogue: transpose O^T via LDS (per-wave 8KB region), write partials
  float* tb = (wave < 2) ? ((float*)&kt[0][0][0][0] + wave * 2048)
                         : ((float*)&vt[0][0][0][0] + (wave - 2) * 2048);
  #pragma unroll
  for (int mt = 0; mt < 2; ++mt) {
    #pragma unroll
    for (int r = 0; r < 16; ++r) {
      int d = mt * 32 + (r & 3) + ((r >> 2) << 3) + (b5 << 2);
      float val = mt ? O1[r] : O0[r];
      tb[l5 * 64 + ((((d >> 2) ^ (l5 & 15)) << 2) | (d & 3))] = val;
    }
  }
  __builtin_amdgcn_s_waitcnt(0);  // conservative: ensure ds_writes visible to own reads
  #pragma unroll
  for (int L = 0; L < 8; ++L) {
    int row = L * 4 + (lane >> 4);                  // q_local 0..31
    int cb  = lane & 15;                            // float4 col block
    float4 val = *(const float4*)&tb[row * 64 + ((cb ^ (row & 15)) << 2)];
    long qg = (long)b * SEQ + qrow0 + row;
    *(float4*)(Opart + ((long)split * (BATCH * SEQ) + qg) * DIM + cb * 4) = val;
  }
  if (lane < 32) {
    long qg = (long)b * SEQ + qrow0 + lane;
    Mpart[(long)split * (BATCH * SEQ) + qg] = m;
    Lpart[(long)split * (BATCH * SEQ) + qg] = lsum;
  }
}

// ---------------- merge KV-split partials ----------------------------------
__global__ __launch_bounds__(256) void merge_kernel(
    const float* __restrict__ Opart, const float* __restrict__ Mpart,
    const float* __restrict__ Lpart, float* __restrict__ Out) {
  int idx = blockIdx.x * 256 + threadIdx.x;  // < 1048576
  int bq = idx >> 6;
  int d  = idx & 63;
  float m0 = Mpart[bq],          m1 = Mpart[16384 + bq];
  float m2 = Mpart[32768 + bq],  m3 = Mpart[49152 + bq];
  float M = fmaxf(fmaxf(m0, m1), fmaxf(m2, m3));
  float w0 = exp2f(m0 - M), w1 = exp2f(m1 - M), w2 = exp2f(m2 - M), w3 = exp2f(m3 - M);
  float L = w0 * Lpart[bq] + w1 * Lpart[16384 + bq]
          + w2 * Lpart[32768 + bq] + w3 * Lpart[49152 + bq];
  float acc = w0 * Opart[(long)bq * 64 + d]
            + w1 * Opart[(long)(16384 + bq) * 64 + d]
            + w2 * Opart[(long)(32768 + bq) * 64 + d]
            + w3 * Opart[(long)(49152 + bq) * 64 + d];
  Out[idx] = acc / L;
}

extern "C" void kernel_launch(void* const* d_in, const int* in_sizes, int n_in,
                              void* d_out, int out_size, void* d_ws, size_t ws_size,
                              hipStream_t stream) {
  const float* Q = (const float*)d_in[0];
  const float* K = (const float*)d_in[1];
  const float* V = (const float*)d_in[2];
  float* Out = (float*)d_out;

  // ws layout: [Khi|Klo|VThi|VTlo] bf16 (8 MB) + Opart (16 MB) + M/L (0.5 MB)
  unsigned short* w16  = (unsigned short*)d_ws;
  unsigned short* Khi  = w16;
  unsigned short* Klo  = w16 + 1048576;
  unsigned short* VThi = w16 + 2097152;
  unsigned short* VTlo = w16 + 3145728;
  float* wsf   = (float*)(w16 + 4194304);
  float* Opart = wsf;                       // 4*16384*64 floats
  float* Mpart = wsf + 4194304;             // 4*16384
  float* Lpart = Mpart + 65536;             // 4*16384

  hipLaunchKernelGGL(prep_kernel, dim3(2048), dim3(256), 0, stream,
                     K, V, Khi, Klo, VThi, VTlo);
  hipLaunchKernelGGL(attn_kernel, dim3(512), dim3(256), 0, stream,
                     Q, Khi, Klo, VThi, VTlo, Opart, Mpart, Lpart);
  hipLaunchKernelGGL(merge_kernel, dim3(4096), dim3(256), 0, stream,
                     Opart, Mpart, Lpart, Out);
}

// Round 2
// 78.345 us; speedup vs baseline: 1.5337x; 1.5337x over previous
//
#include <hip/hip_runtime.h>

// AttentionHead: B=4, S=4096, D=64, fp32 in/out.
// Flash attention, 32x32x16 bf16 MFMA with hi/lo (Dekker) split.
// R2: cvt_pk+permlane32_swap P-pack (no LDS roundtrip), defer-max,
//     global_load_lds staging, NSPLIT=8 (ws-guarded), tiled prep transpose.

#define BATCH 4
#define SEQ   4096
#define DIM   64
#define KVB   32
#define NQ    16384                  // BATCH*SEQ
#define QSCALE 0.18033688011112042f  // (1/sqrt(64)) * log2(e); all exps are exp2

typedef float f32x16 __attribute__((ext_vector_type(16)));
typedef unsigned short u16x8 __attribute__((ext_vector_type(8)));
typedef unsigned int   u32x4 __attribute__((ext_vector_type(4)));

#define MFMA32(a, b, c) __builtin_amdgcn_mfma_f32_32x32x16_bf16((a), (b), (c), 0, 0, 0)

// v_permlane32_swap_b32 vdst, vsrc: vdst.high <-> vsrc.low (lane^32 exchange)
#define PLSWAP(a, b) asm("v_permlane32_swap_b32 %0, %1" : "+v"(a), "+v"(b))

__device__ __forceinline__ unsigned short f2bf(float x) {
  unsigned int u = __float_as_uint(x);
  return (unsigned short)((u + 0x7fffu + ((u >> 16) & 1u)) >> 16);   // RNE
}
__device__ __forceinline__ float bf2f(unsigned short h) {
  return __uint_as_float(((unsigned int)h) << 16);
}
__device__ __forceinline__ unsigned int cvtpk(float a, float b) {  // lo=a, hi=b
  unsigned int r;
  asm("v_cvt_pk_bf16_f32 %0, %1, %2" : "=v"(r) : "v"(a), "v"(b));
  return r;
}
__device__ __forceinline__ float bflo(unsigned int w) { return __uint_as_float(w << 16); }
__device__ __forceinline__ float bfhi(unsigned int w) { return __uint_as_float(w & 0xffff0000u); }

// ---------------- prep: K -> Khi/Klo [B][S][D]; V -> VThi/VTlo [B][D][S] ----
// One block per (b, 64-row s-tile): coalesced in, LDS transpose, coalesced out.
__global__ __launch_bounds__(256) void prep_kernel(
    const float* __restrict__ K, const float* __restrict__ V,
    unsigned short* __restrict__ Khi, unsigned short* __restrict__ Klo,
    unsigned short* __restrict__ VThi, unsigned short* __restrict__ VTlo) {
  __shared__ float tile[64][65];
  const int t = threadIdx.x;
  const int b = blockIdx.x >> 6;
  const int s0 = (blockIdx.x & 63) << 6;
  #pragma unroll
  for (int r = 0; r < 4; ++r) {
    const int s_loc = r * 16 + (t >> 4);
    const int d0 = (t & 15) << 2;
    const long base = ((long)b * SEQ + s0 + s_loc) * DIM + d0;
    const float4 kv = *(const float4*)(K + base);
    const float4 vv = *(const float4*)(V + base);
    tile[s_loc][d0 + 0] = vv.x;
    tile[s_loc][d0 + 1] = vv.y;
    tile[s_loc][d0 + 2] = vv.z;
    tile[s_loc][d0 + 3] = vv.w;
    ushort4 h, l;
    h.x = f2bf(kv.x); l.x = f2bf(kv.x - bf2f(h.x));
    h.y = f2bf(kv.y); l.y = f2bf(kv.y - bf2f(h.y));
    h.z = f2bf(kv.z); l.z = f2bf(kv.z - bf2f(h.z));
    h.w = f2bf(kv.w); l.w = f2bf(kv.w - bf2f(h.w));
    *(ushort4*)(Khi + base) = h;
    *(ushort4*)(Klo + base) = l;
  }
  __syncthreads();
  #pragma unroll
  for (int r = 0; r < 4; ++r) {
    const int d_loc = r * 16 + (t >> 4);
    const int sb = (t & 15) << 2;
    ushort4 h, l;
    float x;
    x = tile[sb + 0][d_loc]; h.x = f2bf(x); l.x = f2bf(x - bf2f(h.x));
    x = tile[sb + 1][d_loc]; h.y = f2bf(x); l.y = f2bf(x - bf2f(h.y));
    x = tile[sb + 2][d_loc]; h.z = f2bf(x); l.z = f2bf(x - bf2f(h.z));
    x = tile[sb + 3][d_loc]; h.w = f2bf(x); l.w = f2bf(x - bf2f(h.w));
    const long obase = (long)b * (DIM * SEQ) + (long)d_loc * SEQ + s0 + sb;
    *(ushort4*)(VThi + obase) = h;
    *(ushort4*)(VTlo + obase) = l;
  }
}

// ---------------- attention main kernel ------------------------------------
// Grid 4*NS*32 WGs; WG = 4 waves (128 q), wave = 32 q; KV tiles of 32 dbuf'd.
template<int NS>
__global__ __launch_bounds__(256, 4) void attn_kernel(
    const float* __restrict__ Q,
    const unsigned short* __restrict__ Khi, const unsigned short* __restrict__ Klo,
    const unsigned short* __restrict__ VThi, const unsigned short* __restrict__ VTlo,
    float* __restrict__ Opart, float* __restrict__ Mpart, float* __restrict__ Lpart) {

  __shared__ __align__(16) unsigned short kt[2][2][KVB][DIM];   // 16 KB
  __shared__ __align__(16) unsigned short vt[2][2][DIM][KVB];   // 16 KB

  constexpr int SPL = SEQ / NS;
  constexpr int NT  = SPL / KVB;
  constexpr int NWG = 4 * NS * 32;
  constexpr int CPX = NWG / 8;

  const int raw = blockIdx.x;
  const int bid = (raw & 7) * CPX + (raw >> 3);   // XCD-contiguous, bijective
  const int b     = bid / (NS * 32);
  const int rem   = bid % (NS * 32);
  const int split = rem >> 5;
  const int qblk  = rem & 31;

  const int tid  = threadIdx.x;
  const int wave = tid >> 6;
  const int lane = tid & 63;
  const int l5   = lane & 31;
  const int b5   = lane >> 5;

  const int qrow0 = qblk * 128 + wave * 32;
  const int kv0   = split * SPL;

  // ---- Q fragments: q row = l5; frag[ch] elem j <-> d = 16*ch + 8*b5 + j ----
  u16x8 qh[4], qlo[4];
  {
    const float* qp = Q + ((long)b * SEQ + qrow0 + l5) * DIM;
    #pragma unroll
    for (int ch = 0; ch < 4; ++ch) {
      const float* p = qp + ch * 16 + b5 * 8;
      float4 x0 = *(const float4*)(p);
      float4 x1 = *(const float4*)(p + 4);
      float vv[8] = {x0.x, x0.y, x0.z, x0.w, x1.x, x1.y, x1.z, x1.w};
      #pragma unroll
      for (int j = 0; j < 8; ++j) {
        float sv = vv[j] * QSCALE;
        unsigned short h = f2bf(sv);
        qh[ch][j]  = h;
        qlo[ch][j] = f2bf(sv - bf2f(h));
      }
    }
  }

  // wave roles: 0->Khi, 1->Klo, 2->VThi, 3->VTlo.  Global src is pre-swizzled
  // so the (linear) global_load_lds dest matches the swizzled read pattern.
  const unsigned short* sArr = (wave == 0) ? Khi : (wave == 1) ? Klo
                             : (wave == 2) ? VThi : VTlo;

  auto stage = [&](int buf, int kb) {
    if (wave < 2) {
      unsigned short* dst = &kt[buf][wave][0][0];
      const long rowbase = (long)b * SEQ + kb;
      #pragma unroll
      for (int L = 0; L < 4; ++L) {
        int key = L * 8 + (lane >> 3);
        int cb  = (lane & 7) ^ (lane >> 3);
        const unsigned short* src = sArr + (rowbase + key) * DIM + cb * 8;
        __builtin_amdgcn_global_load_lds(
            (__attribute__((address_space(1))) void*)src,
            (__attribute__((address_space(3))) void*)(dst + L * 512), 16, 0, 0);
      }
    } else {
      unsigned short* dst = &vt[buf][wave - 2][0][0];
      const long vbase = (long)b * (DIM * SEQ) + kb;
      #pragma unroll
      for (int L = 0; L < 4; ++L) {
        int d  = L * 16 + (lane >> 2);
        int cb = (lane & 3) ^ ((lane >> 3) & 3);
        const unsigned short* src = sArr + vbase + (long)d * SEQ + cb * 8;
        __builtin_amdgcn_global_load_lds(
            (__attribute__((address_space(1))) void*)src,
            (__attribute__((address_space(3))) void*)(dst + L * 512), 16, 0, 0);
      }
    }
  };

  stage(0, kv0);
  __syncthreads();

  f32x16 O0 = {0,0,0,0,0,0,0,0,0,0,0,0,0,0,0,0};
  f32x16 O1 = {0,0,0,0,0,0,0,0,0,0,0,0,0,0,0,0};
  float m = -INFINITY, lsum = 0.0f;

  for (int t = 0; t < NT; ++t) {
    const int cur = t & 1;
    if (t + 1 < NT) stage(cur ^ 1, kv0 + (t + 1) * KVB);   // in flight thru compute

    const unsigned short* ktc = &kt[cur][0][0][0];    // hi; lo at +2048
    const unsigned short* vtc = &vt[cur][0][0][0];

    // ---- QK^T swapped: sacc = S^T, row=key=(r&3)+8*(r>>2)+4*b5, col=q=l5 ----
    f32x16 sacc = {0,0,0,0,0,0,0,0,0,0,0,0,0,0,0,0};
    #pragma unroll
    for (int ch = 0; ch < 4; ++ch) {
      int off = l5 * DIM + ((((ch << 1) | b5) ^ (l5 & 7)) << 3);
      u16x8 kh = *(const u16x8*)(ktc + off);
      u16x8 kl = *(const u16x8*)(ktc + 2048 + off);
      sacc = MFMA32(kh, qh[ch],  sacc);
      sacc = MFMA32(kl, qh[ch],  sacc);
      sacc = MFMA32(kh, qlo[ch], sacc);
    }

    // ---- online softmax with defer-max (T13) -------------------------------
    float smax = sacc[0];
    #pragma unroll
    for (int r = 1; r < 16; ++r) smax = fmaxf(smax, sacc[r]);
    smax = fmaxf(smax, __shfl_xor(smax, 32));
    if (!__all(smax <= m + 8.0f)) {
      float mn = fmaxf(m, smax);
      float fs = exp2f(m - mn);
      m = mn;
      lsum *= fs;
      #pragma unroll
      for (int r = 0; r < 16; ++r) { O0[r] *= fs; O1[r] *= fs; }
    }
    float p[16];
    float ps = 0.0f;
    #pragma unroll
    for (int r = 0; r < 16; ++r) { p[r] = exp2f(sacc[r] - m); ps += p[r]; }
    ps += __shfl_xor(ps, 32);
    lsum += ps;

    // ---- P -> bf16 hi/lo B-fragments via cvt_pk + permlane32_swap (T12) ----
    // key(p[r]) = (r&3) + 8*(r>>2) + 4*b5; frag[kc] elem j <-> key 16kc+8b5+j
    u16x8 pbh[2], pbl[2];
    #pragma unroll
    for (int kc = 0; kc < 2; ++kc) {
      const int o = kc * 8;
      unsigned int x0 = cvtpk(p[o+0], p[o+1]);
      unsigned int x1 = cvtpk(p[o+2], p[o+3]);
      unsigned int y0 = cvtpk(p[o+4], p[o+5]);
      unsigned int y1 = cvtpk(p[o+6], p[o+7]);
      unsigned int lx0 = cvtpk(p[o+0] - bflo(x0), p[o+1] - bfhi(x0));
      unsigned int lx1 = cvtpk(p[o+2] - bflo(x1), p[o+3] - bfhi(x1));
      unsigned int ly0 = cvtpk(p[o+4] - bflo(y0), p[o+5] - bfhi(y0));
      unsigned int ly1 = cvtpk(p[o+6] - bflo(y1), p[o+7] - bfhi(y1));
      PLSWAP(x0, y0);   // x0 -> frag word0, y0 -> frag word2
      PLSWAP(x1, y1);   // x1 -> word1, y1 -> word3
      PLSWAP(lx0, ly0);
      PLSWAP(lx1, ly1);
      u32x4 hw = {x0, x1, y0, y1};
      u32x4 lw = {lx0, lx1, ly0, ly1};
      pbh[kc] = __builtin_bit_cast(u16x8, hw);
      pbl[kc] = __builtin_bit_cast(u16x8, lw);
    }

    // ---- PV: O^T[d][q] += V^T * P^T (3 split terms) ------------------------
    #pragma unroll
    for (int mt = 0; mt < 2; ++mt) {
      f32x16 Oa = mt ? O1 : O0;
      int d = mt * 32 + l5;
      #pragma unroll
      for (int kc = 0; kc < 2; ++kc) {
        int off = d * 32 + ((((kc << 1) | b5) ^ ((d >> 1) & 3)) << 3);
        u16x8 vh = *(const u16x8*)(vtc + off);
        u16x8 vl = *(const u16x8*)(vtc + 2048 + off);
        Oa = MFMA32(vh, pbh[kc], Oa);
        Oa = MFMA32(vh, pbl[kc], Oa);
        Oa = MFMA32(vl, pbh[kc], Oa);
      }
      if (mt) O1 = Oa; else O0 = Oa;
    }

    __syncthreads();   // drains staging vmcnt + all LDS reads of buf cur
  }

  // ---- epilogue: transpose O^T via LDS (per-wave 8KB region), write partials
  float* tb = (wave < 2) ? ((float*)kt + wave * 2048)
                         : ((float*)vt + (wave - 2) * 2048);
  #pragma unroll
  for (int mt = 0; mt < 2; ++mt) {
    #pragma unroll
    for (int r = 0; r < 16; ++r) {
      int d = mt * 32 + (r & 3) + ((r >> 2) << 3) + (b5 << 2);
      float val = mt ? O1[r] : O0[r];
      tb[l5 * 64 + ((((d >> 2) ^ (l5 & 15)) << 2) | (d & 3))] = val;
    }
  }
  __builtin_amdgcn_s_waitcnt(0);   // same-wave ds_write -> ds_read ordering
  #pragma unroll
  for (int L = 0; L < 8; ++L) {
    int row = L * 4 + (lane >> 4);                  // q_local 0..31
    int cb  = lane & 15;
    float4 val = *(const float4*)&tb[row * 64 + ((cb ^ (row & 15)) << 2)];
    long qg = (long)b * SEQ + qrow0 + row;
    *(float4*)(Opart + ((long)split * NQ + qg) * DIM + cb * 4) = val;
  }
  if (lane < 32) {
    long qg = (long)b * SEQ + qrow0 + lane;
    Mpart[(long)split * NQ + qg] = m;
    Lpart[(long)split * NQ + qg] = lsum;
  }
}

// ---------------- merge KV-split partials ----------------------------------
template<int NS>
__global__ __launch_bounds__(256) void merge_kernel(
    const float* __restrict__ Opart, const float* __restrict__ Mpart,
    const float* __restrict__ Lpart, float* __restrict__ Out) {
  int idx = blockIdx.x * 256 + threadIdx.x;  // over NQ*16
  int bq = idx >> 4;
  int d4 = (idx & 15) << 2;
  float ms[NS];
  float M = -INFINITY;
  #pragma unroll
  for (int s = 0; s < NS; ++s) { ms[s] = Mpart[s * NQ + bq]; M = fmaxf(M, ms[s]); }
  float L = 0.0f;
  float4 acc = {0, 0, 0, 0};
  #pragma unroll
  for (int s = 0; s < NS; ++s) {
    float w = exp2f(ms[s] - M);
    L += w * Lpart[s * NQ + bq];
    float4 o = *(const float4*)(Opart + ((long)(s * NQ + bq)) * DIM + d4);
    acc.x += w * o.x; acc.y += w * o.y; acc.z += w * o.z; acc.w += w * o.w;
  }
  float inv = 1.0f / L;
  float4 r = {acc.x * inv, acc.y * inv, acc.z * inv, acc.w * inv};
  *(float4*)(Out + (long)bq * DIM + d4) = r;
}

extern "C" void kernel_launch(void* const* d_in, const int* in_sizes, int n_in,
                              void* d_out, int out_size, void* d_ws, size_t ws_size,
                              hipStream_t stream) {
  const float* Q = (const float*)d_in[0];
  const float* K = (const float*)d_in[1];
  const float* V = (const float*)d_in[2];
  float* Out = (float*)d_out;

  // ws: [Khi|Klo|VThi|VTlo] bf16 (8 MB) + Opart (NS*4MB) + M/L
  unsigned short* w16  = (unsigned short*)d_ws;
  unsigned short* Khi  = w16;
  unsigned short* Klo  = w16 + 1048576;
  unsigned short* VThi = w16 + 2097152;
  unsigned short* VTlo = w16 + 3145728;
  float* wsf = (float*)(w16 + 4194304);

  const size_t need8 = (size_t)8 * 1024 * 1024 + (size_t)8 * NQ * DIM * 4 + (size_t)2 * 8 * NQ * 4;
  const int ns = (ws_size >= need8) ? 8 : 4;

  prep_kernel<<<dim3(256), dim3(256), 0, stream>>>(K, V, Khi, Klo, VThi, VTlo);
  if (ns == 8) {
    float* Opart = wsf;
    float* Mpart = wsf + (size_t)8 * NQ * DIM;
    float* Lpart = Mpart + 8 * NQ;
    attn_kernel<8><<<dim3(1024), dim3(256), 0, stream>>>(Q, Khi, Klo, VThi, VTlo, Opart, Mpart, Lpart);
    merge_kernel<8><<<dim3(1024), dim3(256), 0, stream>>>(Opart, Mpart, Lpart, Out);
  } else {
    float* Opart = wsf;
    float* Mpart = wsf + (size_t)4 * NQ * DIM;
    float* Lpart = Mpart + 4 * NQ;
    attn_kernel<4><<<dim3(512), dim3(256), 0, stream>>>(Q, Khi, Klo, VThi, VTlo, Opart, Mpart, Lpart);
    merge_kernel<4><<<dim3(1024), dim3(256), 0, stream>>>(Opart, Mpart, Lpart, Out);
  }
}

// Round 5
// 74.068 us; speedup vs baseline: 1.6222x; 1.0577x over previous
//
#include <hip/hip_runtime.h>

// AttentionHead: B=4, S=4096, D=64, fp32 in/out.
// Flash attention, 32x32x16 bf16 MFMA with hi/lo (Dekker) split.
// R5 = R4 but ALL permlane32_swap via __builtin_amdgcn_permlane32_swap
// (inline-asm permlane bypassed the compiler's hazard recognizer ->
// VALU-write->permlane-read wait-states missing -> stale reads; builtin
// lets the compiler insert the required s_nops and handle tied defs).

#define BATCH 4
#define SEQ   4096
#define DIM   64
#define KVB   32
#define NQ    16384                  // BATCH*SEQ
#define QSCALE 0.18033688011112042f  // (1/sqrt(64)) * log2(e); all exps are exp2

typedef float f32x16 __attribute__((ext_vector_type(16)));
typedef unsigned short u16x8 __attribute__((ext_vector_type(8)));
typedef unsigned int   u32x4 __attribute__((ext_vector_type(4)));
typedef unsigned int   u32x2 __attribute__((ext_vector_type(2)));

#define MFMA32(a, b, c) __builtin_amdgcn_mfma_f32_32x32x16_bf16((a), (b), (c), 0, 0, 0)

#if __has_builtin(__builtin_amdgcn_permlane32_swap)
#define HAVE_PLSWAP 1
#else
#define HAVE_PLSWAP 0
#endif

// Exchange a.high32lanes <-> b.low32lanes (the v_permlane32_swap_b32 op).
__device__ __forceinline__ void plswap(unsigned int& a, unsigned int& b) {
#if HAVE_PLSWAP
  u32x2 r = __builtin_amdgcn_permlane32_swap(a, b, false, false);
  a = r[0]; b = r[1];
#else
  unsigned int sa_ = (unsigned int)__shfl_xor((int)a, 32);
  unsigned int sb_ = (unsigned int)__shfl_xor((int)b, 32);
  bool lo = ((threadIdx.x & 63) < 32);
  unsigned int na = lo ? a : sb_;
  unsigned int nb = lo ? sa_ : b;
  a = na; b = nb;
#endif
}

// (own, partner) value pair across the lane^32 split (order per half varies,
// but both uses are symmetric reductions: max / sum).
__device__ __forceinline__ void xswap32f(float x, float& a, float& b) {
  unsigned int u = __float_as_uint(x), v = u;
  plswap(u, v);
  a = __uint_as_float(u); b = __uint_as_float(v);
}

#define EXP2F(x) __builtin_amdgcn_exp2f(x)

__device__ __forceinline__ unsigned short f2bf(float x) {
  unsigned int u = __float_as_uint(x);
  return (unsigned short)((u + 0x7fffu + ((u >> 16) & 1u)) >> 16);   // RNE
}
__device__ __forceinline__ float bf2f(unsigned short h) {
  return __uint_as_float(((unsigned int)h) << 16);
}
__device__ __forceinline__ unsigned int cvtpk(float a, float b) {  // lo=a, hi=b
  unsigned int r;
  asm("v_cvt_pk_bf16_f32 %0, %1, %2" : "=v"(r) : "v"(a), "v"(b));
  return r;
}
__device__ __forceinline__ float bflo(unsigned int w) { return __uint_as_float(w << 16); }
__device__ __forceinline__ float bfhi(unsigned int w) { return __uint_as_float(w & 0xffff0000u); }

// ---------------- prep: K -> Khi/Klo [B][S][D]; V -> VThi/VTlo [B][D][S] ----
__global__ __launch_bounds__(256) void prep_kernel(
    const float* __restrict__ K, const float* __restrict__ V,
    unsigned short* __restrict__ Khi, unsigned short* __restrict__ Klo,
    unsigned short* __restrict__ VThi, unsigned short* __restrict__ VTlo) {
  __shared__ float tile[64][65];
  const int t = threadIdx.x;
  const int b = blockIdx.x >> 6;
  const int s0 = (blockIdx.x & 63) << 6;
  #pragma unroll
  for (int r = 0; r < 4; ++r) {
    const int s_loc = r * 16 + (t >> 4);
    const int d0 = (t & 15) << 2;
    const long base = ((long)b * SEQ + s0 + s_loc) * DIM + d0;
    const float4 kv = *(const float4*)(K + base);
    const float4 vv = *(const float4*)(V + base);
    tile[s_loc][d0 + 0] = vv.x;
    tile[s_loc][d0 + 1] = vv.y;
    tile[s_loc][d0 + 2] = vv.z;
    tile[s_loc][d0 + 3] = vv.w;
    ushort4 h, l;
    h.x = f2bf(kv.x); l.x = f2bf(kv.x - bf2f(h.x));
    h.y = f2bf(kv.y); l.y = f2bf(kv.y - bf2f(h.y));
    h.z = f2bf(kv.z); l.z = f2bf(kv.z - bf2f(h.z));
    h.w = f2bf(kv.w); l.w = f2bf(kv.w - bf2f(h.w));
    *(ushort4*)(Khi + base) = h;
    *(ushort4*)(Klo + base) = l;
  }
  __syncthreads();
  #pragma unroll
  for (int r = 0; r < 4; ++r) {
    const int d_loc = r * 16 + (t >> 4);
    const int sb = (t & 15) << 2;
    ushort4 h, l;
    float x;
    x = tile[sb + 0][d_loc]; h.x = f2bf(x); l.x = f2bf(x - bf2f(h.x));
    x = tile[sb + 1][d_loc]; h.y = f2bf(x); l.y = f2bf(x - bf2f(h.y));
    x = tile[sb + 2][d_loc]; h.z = f2bf(x); l.z = f2bf(x - bf2f(h.z));
    x = tile[sb + 3][d_loc]; h.w = f2bf(x); l.w = f2bf(x - bf2f(h.w));
    const long obase = (long)b * (DIM * SEQ) + (long)d_loc * SEQ + s0 + sb;
    *(ushort4*)(VThi + obase) = h;
    *(ushort4*)(VTlo + obase) = l;
  }
}

// ---------------- attention main kernel ------------------------------------
template<int NS>
__global__ __launch_bounds__(256, 4) void attn_kernel(
    const float* __restrict__ Q,
    const unsigned short* __restrict__ Khi, const unsigned short* __restrict__ Klo,
    const unsigned short* __restrict__ VThi, const unsigned short* __restrict__ VTlo,
    float* __restrict__ Opart, float* __restrict__ Mpart, float* __restrict__ Lpart) {

  __shared__ __align__(16) unsigned short kt[2][2][KVB][DIM];   // 16 KB
  __shared__ __align__(16) unsigned short vt[2][2][DIM][KVB];   // 16 KB

  constexpr int SPL = SEQ / NS;
  constexpr int NT  = SPL / KVB;
  constexpr int NWG = 4 * NS * 32;
  constexpr int CPX = NWG / 8;

  const int raw = blockIdx.x;
  const int bid = (raw & 7) * CPX + (raw >> 3);   // XCD-contiguous, bijective
  const int b     = bid / (NS * 32);
  const int rem   = bid % (NS * 32);
  const int split = rem >> 5;
  const int qblk  = rem & 31;

  const int tid  = threadIdx.x;
  const int wave = tid >> 6;
  const int lane = tid & 63;
  const int l5   = lane & 31;
  const int b5   = lane >> 5;

  const int qrow0 = qblk * 128 + wave * 32;
  const int kv0   = split * SPL;

  // ---- Q fragments: q row = l5; frag[ch] elem j <-> d = 16*ch + 8*b5 + j ----
  u16x8 qh[4], qlo[4];
  {
    const float* qp = Q + ((long)b * SEQ + qrow0 + l5) * DIM;
    #pragma unroll
    for (int ch = 0; ch < 4; ++ch) {
      const float* p = qp + ch * 16 + b5 * 8;
      float4 x0 = *(const float4*)(p);
      float4 x1 = *(const float4*)(p + 4);
      float vv[8] = {x0.x, x0.y, x0.z, x0.w, x1.x, x1.y, x1.z, x1.w};
      #pragma unroll
      for (int j = 0; j < 8; ++j) {
        float sv = vv[j] * QSCALE;
        unsigned short h = f2bf(sv);
        qh[ch][j]  = h;
        qlo[ch][j] = f2bf(sv - bf2f(h));
      }
    }
  }

  // wave roles: 0->Khi, 1->Klo, 2->VThi, 3->VTlo; pre-swizzled global source,
  // linear global_load_lds dest.
  const unsigned short* sArr = (wave == 0) ? Khi : (wave == 1) ? Klo
                             : (wave == 2) ? VThi : VTlo;

  auto stage = [&](int buf, int kb) {
    if (wave < 2) {
      unsigned short* dst = &kt[buf][wave][0][0];
      const long rowbase = (long)b * SEQ + kb;
      #pragma unroll
      for (int L = 0; L < 4; ++L) {
        int key = L * 8 + (lane >> 3);
        int cb  = (lane & 7) ^ (lane >> 3);
        const unsigned short* src = sArr + (rowbase + key) * DIM + cb * 8;
        __builtin_amdgcn_global_load_lds(
            (__attribute__((address_space(1))) void*)src,
            (__attribute__((address_space(3))) void*)(dst + L * 512), 16, 0, 0);
      }
    } else {
      unsigned short* dst = &vt[buf][wave - 2][0][0];
      const long vbase = (long)b * (DIM * SEQ) + kb;
      #pragma unroll
      for (int L = 0; L < 4; ++L) {
        int d  = L * 16 + (lane >> 2);
        int cb = (lane & 3) ^ ((lane >> 3) & 3);
        const unsigned short* src = sArr + vbase + (long)d * SEQ + cb * 8;
        __builtin_amdgcn_global_load_lds(
            (__attribute__((address_space(1))) void*)src,
            (__attribute__((address_space(3))) void*)(dst + L * 512), 16, 0, 0);
      }
    }
  };

  stage(0, kv0);
  __syncthreads();

  f32x16 O0 = {0,0,0,0,0,0,0,0,0,0,0,0,0,0,0,0};
  f32x16 O1 = {0,0,0,0,0,0,0,0,0,0,0,0,0,0,0,0};
  float m = -INFINITY, lsum = 0.0f;

  for (int t = 0; t < NT; ++t) {
    const int cur = t & 1;
    if (t + 1 < NT) stage(cur ^ 1, kv0 + (t + 1) * KVB);

    const unsigned short* ktc = &kt[cur][0][0][0];    // hi; lo at +2048
    const unsigned short* vtc = &vt[cur][0][0][0];

    // ---- QK^T swapped, two independent 6-chains --------------------------
    // sacc = S^T: row=key=(r&3)+8*(r>>2)+4*b5, col=q=l5
    f32x16 sa = {0,0,0,0,0,0,0,0,0,0,0,0,0,0,0,0};
    f32x16 sb = {0,0,0,0,0,0,0,0,0,0,0,0,0,0,0,0};
    __builtin_amdgcn_s_setprio(1);
    #pragma unroll
    for (int ch = 0; ch < 2; ++ch) {
      int off = l5 * DIM + ((((ch << 1) | b5) ^ (l5 & 7)) << 3);
      u16x8 kh = *(const u16x8*)(ktc + off);
      u16x8 kl = *(const u16x8*)(ktc + 2048 + off);
      sa = MFMA32(kh, qh[ch],  sa);
      sa = MFMA32(kl, qh[ch],  sa);
      sa = MFMA32(kh, qlo[ch], sa);
    }
    #pragma unroll
    for (int ch = 2; ch < 4; ++ch) {
      int off = l5 * DIM + ((((ch << 1) | b5) ^ (l5 & 7)) << 3);
      u16x8 kh = *(const u16x8*)(ktc + off);
      u16x8 kl = *(const u16x8*)(ktc + 2048 + off);
      sb = MFMA32(kh, qh[ch],  sb);
      sb = MFMA32(kl, qh[ch],  sb);
      sb = MFMA32(kh, qlo[ch], sb);
    }
    __builtin_amdgcn_s_setprio(0);

    float s[16];
    #pragma unroll
    for (int r = 0; r < 16; ++r) s[r] = sa[r] + sb[r];

    // ---- online softmax: tree max, builtin cross-32 pair, defer-max -------
    float x0 = fmaxf(s[0], s[1]),  x1 = fmaxf(s[2], s[3]);
    float x2 = fmaxf(s[4], s[5]),  x3 = fmaxf(s[6], s[7]);
    float x4 = fmaxf(s[8], s[9]),  x5 = fmaxf(s[10], s[11]);
    float x6 = fmaxf(s[12], s[13]), x7 = fmaxf(s[14], s[15]);
    float y0 = fmaxf(fmaxf(x0, x1), fmaxf(x2, x3));
    float y1 = fmaxf(fmaxf(x4, x5), fmaxf(x6, x7));
    float sm = fmaxf(y0, y1);
    float pa, pb;
    xswap32f(sm, pa, pb);
    float smax = fmaxf(pa, pb);

    if (!__all(smax <= m + 8.0f)) {
      float mn = fmaxf(m, smax);
      float fs = EXP2F(m - mn);
      m = mn;
      lsum *= fs;
      #pragma unroll
      for (int r = 0; r < 16; ++r) { O0[r] *= fs; O1[r] *= fs; }
    }
    float p[16];
    #pragma unroll
    for (int r = 0; r < 16; ++r) p[r] = EXP2F(s[r] - m);
    float a0 = (p[0] + p[1]) + (p[2] + p[3]);
    float a1 = (p[4] + p[5]) + (p[6] + p[7]);
    float a2 = (p[8] + p[9]) + (p[10] + p[11]);
    float a3 = (p[12] + p[13]) + (p[14] + p[15]);
    float ps = (a0 + a1) + (a2 + a3);
    float qa, qb;
    xswap32f(ps, qa, qb);
    lsum += qa + qb;

    // ---- P -> bf16 hi/lo B-fragments via cvt_pk + permlane32_swap (T12) ----
    u16x8 pbh[2], pbl[2];
    #pragma unroll
    for (int kc = 0; kc < 2; ++kc) {
      const int o = kc * 8;
      unsigned int x0w = cvtpk(p[o+0], p[o+1]);
      unsigned int x1w = cvtpk(p[o+2], p[o+3]);
      unsigned int y0w = cvtpk(p[o+4], p[o+5]);
      unsigned int y1w = cvtpk(p[o+6], p[o+7]);
      unsigned int lx0 = cvtpk(p[o+0] - bflo(x0w), p[o+1] - bfhi(x0w));
      unsigned int lx1 = cvtpk(p[o+2] - bflo(x1w), p[o+3] - bfhi(x1w));
      unsigned int ly0 = cvtpk(p[o+4] - bflo(y0w), p[o+5] - bfhi(y0w));
      unsigned int ly1 = cvtpk(p[o+6] - bflo(y1w), p[o+7] - bfhi(y1w));
      plswap(x0w, y0w);
      plswap(x1w, y1w);
      plswap(lx0, ly0);
      plswap(lx1, ly1);
      u32x4 hw = {x0w, x1w, y0w, y1w};
      u32x4 lw = {lx0, lx1, ly0, ly1};
      pbh[kc] = __builtin_bit_cast(u16x8, hw);
      pbl[kc] = __builtin_bit_cast(u16x8, lw);
    }

    // ---- PV: two interleaved 6-chains (O0: d=l5, O1: d=32+l5) -------------
    __builtin_amdgcn_s_setprio(1);
    #pragma unroll
    for (int kc = 0; kc < 2; ++kc) {
      int off = l5 * 32 + ((((kc << 1) | b5) ^ ((l5 >> 1) & 3)) << 3);
      u16x8 vh0 = *(const u16x8*)(vtc + off);
      u16x8 vl0 = *(const u16x8*)(vtc + 2048 + off);
      u16x8 vh1 = *(const u16x8*)(vtc + 1024 + off);        // d+32: same swz
      u16x8 vl1 = *(const u16x8*)(vtc + 3072 + off);
      O0 = MFMA32(vh0, pbh[kc], O0);
      O1 = MFMA32(vh1, pbh[kc], O1);
      O0 = MFMA32(vh0, pbl[kc], O0);
      O1 = MFMA32(vh1, pbl[kc], O1);
      O0 = MFMA32(vl0, pbh[kc], O0);
      O1 = MFMA32(vl1, pbh[kc], O1);
    }
    __builtin_amdgcn_s_setprio(0);

    __syncthreads();   // drains staging vmcnt + all LDS reads of buf cur
  }

  // ---- epilogue: transpose O^T via LDS (per-wave 8KB region), write partials
  float* tb = (wave < 2) ? ((float*)kt + wave * 2048)
                         : ((float*)vt + (wave - 2) * 2048);
  #pragma unroll
  for (int mt = 0; mt < 2; ++mt) {
    #pragma unroll
    for (int r = 0; r < 16; ++r) {
      int d = mt * 32 + (r & 3) + ((r >> 2) << 3) + (b5 << 2);
      float val = mt ? O1[r] : O0[r];
      tb[l5 * 64 + ((((d >> 2) ^ (l5 & 15)) << 2) | (d & 3))] = val;
    }
  }
  __builtin_amdgcn_s_waitcnt(0);
  #pragma unroll
  for (int L = 0; L < 8; ++L) {
    int row = L * 4 + (lane >> 4);
    int cb  = lane & 15;
    float4 val = *(const float4*)&tb[row * 64 + ((cb ^ (row & 15)) << 2)];
    long qg = (long)b * SEQ + qrow0 + row;
    *(float4*)(Opart + ((long)split * NQ + qg) * DIM + cb * 4) = val;
  }
  if (lane < 32) {
    long qg = (long)b * SEQ + qrow0 + lane;
    Mpart[(long)split * NQ + qg] = m;
    Lpart[(long)split * NQ + qg] = lsum;
  }
}

// ---------------- merge KV-split partials ----------------------------------
template<int NS>
__global__ __launch_bounds__(256) void merge_kernel(
    const float* __restrict__ Opart, const float* __restrict__ Mpart,
    const float* __restrict__ Lpart, float* __restrict__ Out) {
  int idx = blockIdx.x * 256 + threadIdx.x;  // over NQ*16
  int bq = idx >> 4;
  int d4 = (idx & 15) << 2;
  float ms[NS];
  float M = -INFINITY;
  #pragma unroll
  for (int s = 0; s < NS; ++s) { ms[s] = Mpart[s * NQ + bq]; M = fmaxf(M, ms[s]); }
  float L = 0.0f;
  float4 acc = {0, 0, 0, 0};
  #pragma unroll
  for (int s = 0; s < NS; ++s) {
    float w = EXP2F(ms[s] - M);
    L += w * Lpart[s * NQ + bq];
    float4 o = *(const float4*)(Opart + ((long)(s * NQ + bq)) * DIM + d4);
    acc.x += w * o.x; acc.y += w * o.y; acc.z += w * o.z; acc.w += w * o.w;
  }
  float inv = 1.0f / L;
  float4 r = {acc.x * inv, acc.y * inv, acc.z * inv, acc.w * inv};
  *(float4*)(Out + (long)bq * DIM + d4) = r;
}

extern "C" void kernel_launch(void* const* d_in, const int* in_sizes, int n_in,
                              void* d_out, int out_size, void* d_ws, size_t ws_size,
                              hipStream_t stream) {
  const float* Q = (const float*)d_in[0];
  const float* K = (const float*)d_in[1];
  const float* V = (const float*)d_in[2];
  float* Out = (float*)d_out;

  unsigned short* w16  = (unsigned short*)d_ws;
  unsigned short* Khi  = w16;
  unsigned short* Klo  = w16 + 1048576;
  unsigned short* VThi = w16 + 2097152;
  unsigned short* VTlo = w16 + 3145728;
  float* wsf = (float*)(w16 + 4194304);

  const size_t need8 = (size_t)8 * 1024 * 1024 + (size_t)8 * NQ * DIM * 4 + (size_t)2 * 8 * NQ * 4;
  const int ns = (ws_size >= need8) ? 8 : 4;

  prep_kernel<<<dim3(256), dim3(256), 0, stream>>>(K, V, Khi, Klo, VThi, VTlo);
  if (ns == 8) {
    float* Opart = wsf;
    float* Mpart = wsf + (size_t)8 * NQ * DIM;
    float* Lpart = Mpart + 8 * NQ;
    attn_kernel<8><<<dim3(1024), dim3(256), 0, stream>>>(Q, Khi, Klo, VThi, VTlo, Opart, Mpart, Lpart);
    merge_kernel<8><<<dim3(1024), dim3(256), 0, stream>>>(Opart, Mpart, Lpart, Out);
  } else {
    float* Opart = wsf;
    float* Mpart = wsf + (size_t)4 * NQ * DIM;
    float* Lpart = Mpart + 4 * NQ;
    attn_kernel<4><<<dim3(512), dim3(256), 0, stream>>>(Q, Khi, Klo, VThi, VTlo, Opart, Mpart, Lpart);
    merge_kernel<4><<<dim3(1024), dim3(256), 0, stream>>>(Opart, Mpart, Lpart, Out);
  }
}

// Round 6
// 51.889 us; speedup vs baseline: 2.3157x; 1.4274x over previous
//
#include <hip/hip_runtime.h>

// AttentionHead: B=4, S=4096, D=64, fp32 in/out.
// R6: pure-bf16 flash attention (Dekker split dropped — softmax dilution
// analysis shows each lo-term contributes <4e-4 absmax on gaussian data).
// KVB=64, single-acc MFMA chains, lane-local lsum, row-XOR LDS swizzle.

#define BATCH 4
#define SEQ   4096
#define DIM   64
#define KVB   64
#define NQ    16384                  // BATCH*SEQ
#define QSCALE 0.18033688011112042f  // (1/sqrt(64)) * log2(e); all exps are exp2

typedef float f32x16 __attribute__((ext_vector_type(16)));
typedef unsigned short u16x8 __attribute__((ext_vector_type(8)));
typedef unsigned int   u32x4 __attribute__((ext_vector_type(4)));
typedef unsigned int   u32x2 __attribute__((ext_vector_type(2)));

#define MFMA32(a, b, c) __builtin_amdgcn_mfma_f32_32x32x16_bf16((a), (b), (c), 0, 0, 0)
#define EXP2F(x) __builtin_amdgcn_exp2f(x)

__device__ __forceinline__ void plswap(unsigned int& a, unsigned int& b) {
  u32x2 r = __builtin_amdgcn_permlane32_swap(a, b, false, false);
  a = r[0]; b = r[1];
}
__device__ __forceinline__ void xswap32f(float x, float& a, float& b) {
  unsigned int u = __float_as_uint(x), v = u;
  plswap(u, v);
  a = __uint_as_float(u); b = __uint_as_float(v);
}

__device__ __forceinline__ unsigned short f2bf(float x) {
  unsigned int u = __float_as_uint(x);
  return (unsigned short)((u + 0x7fffu + ((u >> 16) & 1u)) >> 16);   // RNE
}
__device__ __forceinline__ unsigned int cvtpk(float a, float b) {  // lo=a, hi=b
  unsigned int r;
  asm("v_cvt_pk_bf16_f32 %0, %1, %2" : "=v"(r) : "v"(a), "v"(b));
  return r;
}

// ---------------- prep: K -> Khi [B][S][D]; V -> VThi [B][D][S] -------------
__global__ __launch_bounds__(256) void prep_kernel(
    const float* __restrict__ K, const float* __restrict__ V,
    unsigned short* __restrict__ Khi, unsigned short* __restrict__ VThi) {
  __shared__ float tile[64][65];
  const int t = threadIdx.x;
  const int b = blockIdx.x >> 6;
  const int s0 = (blockIdx.x & 63) << 6;
  #pragma unroll
  for (int r = 0; r < 4; ++r) {
    const int s_loc = r * 16 + (t >> 4);
    const int d0 = (t & 15) << 2;
    const long base = ((long)b * SEQ + s0 + s_loc) * DIM + d0;
    const float4 kv = *(const float4*)(K + base);
    const float4 vv = *(const float4*)(V + base);
    tile[s_loc][d0 + 0] = vv.x;
    tile[s_loc][d0 + 1] = vv.y;
    tile[s_loc][d0 + 2] = vv.z;
    tile[s_loc][d0 + 3] = vv.w;
    ushort4 h;
    h.x = f2bf(kv.x); h.y = f2bf(kv.y); h.z = f2bf(kv.z); h.w = f2bf(kv.w);
    *(ushort4*)(Khi + base) = h;
  }
  __syncthreads();
  #pragma unroll
  for (int r = 0; r < 4; ++r) {
    const int d_loc = r * 16 + (t >> 4);
    const int sb = (t & 15) << 2;
    ushort4 h;
    h.x = f2bf(tile[sb + 0][d_loc]);
    h.y = f2bf(tile[sb + 1][d_loc]);
    h.z = f2bf(tile[sb + 2][d_loc]);
    h.w = f2bf(tile[sb + 3][d_loc]);
    const long obase = (long)b * (DIM * SEQ) + (long)d_loc * SEQ + s0 + sb;
    *(ushort4*)(VThi + obase) = h;
  }
}

// ---------------- attention main kernel ------------------------------------
// LDS layout (both kt and vt): tile[64 rows][64 cols] bf16, 128B/row.
// Physical col-block P = c ^ sigma(row), sigma(r) = (r&7) ^ ((r>>3)&3).
template<int NS>
__global__ __launch_bounds__(256, 4) void attn_kernel(
    const float* __restrict__ Q,
    const unsigned short* __restrict__ Khi, const unsigned short* __restrict__ VThi,
    float* __restrict__ Opart, float* __restrict__ Mpart, float* __restrict__ Lpart) {

  __shared__ __align__(16) unsigned short kt[2][64 * 64];   // 16 KB
  __shared__ __align__(16) unsigned short vt[2][64 * 64];   // 16 KB

  constexpr int SPL = SEQ / NS;
  constexpr int NT  = SPL / KVB;
  constexpr int NWG = 4 * NS * 32;
  constexpr int CPX = NWG / 8;

  const int raw = blockIdx.x;
  const int bid = (raw & 7) * CPX + (raw >> 3);   // XCD-contiguous, bijective
  const int b     = bid / (NS * 32);
  const int rem   = bid % (NS * 32);
  const int split = rem >> 5;
  const int qblk  = rem & 31;

  const int tid  = threadIdx.x;
  const int wave = tid >> 6;
  const int lane = tid & 63;
  const int l5   = lane & 31;
  const int b5   = lane >> 5;

  const int qrow0 = qblk * 128 + wave * 32;
  const int kv0   = split * SPL;

  // ---- Q fragments: q row = l5; frag[ch] elem j <-> d = 16*ch + 8*b5 + j ----
  u16x8 qh[4];
  {
    const float* qp = Q + ((long)b * SEQ + qrow0 + l5) * DIM;
    #pragma unroll
    for (int ch = 0; ch < 4; ++ch) {
      const float* p = qp + ch * 16 + b5 * 8;
      float4 x0 = *(const float4*)(p);
      float4 x1 = *(const float4*)(p + 4);
      u32x4 qw = {cvtpk(x0.x * QSCALE, x0.y * QSCALE),
                  cvtpk(x0.z * QSCALE, x0.w * QSCALE),
                  cvtpk(x1.x * QSCALE, x1.y * QSCALE),
                  cvtpk(x1.z * QSCALE, x1.w * QSCALE)};
      qh[ch] = __builtin_bit_cast(u16x8, qw);
    }
  }

  // staging roles: wave&1 selects K/V, wave>>1 selects which 4 of 8 loads
  const int kvrole = wave & 1;
  const int lbase  = (wave >> 1) * 4;
  const unsigned short* sArr = kvrole ? VThi : Khi;

  auto stage = [&](int buf, int kb) {
    unsigned short* dst = kvrole ? &vt[buf][0] : &kt[buf][0];
    #pragma unroll
    for (int i = 0; i < 4; ++i) {
      const int L = lbase + i;
      const int row = L * 8 + (lane >> 3);
      const int cb  = (lane & 7) ^ (lane >> 3) ^ (L & 3);   // logical col-block
      const unsigned short* src = kvrole
          ? sArr + (long)b * (DIM * SEQ) + (long)row * SEQ + kb + cb * 8
          : sArr + ((long)b * SEQ + kb + row) * DIM + cb * 8;
      __builtin_amdgcn_global_load_lds(
          (__attribute__((address_space(1))) void*)src,
          (__attribute__((address_space(3))) void*)(dst + L * 512), 16, 0, 0);
    }
  };

  stage(0, kv0);
  __syncthreads();

  f32x16 O0 = {0,0,0,0,0,0,0,0,0,0,0,0,0,0,0,0};
  f32x16 O1 = {0,0,0,0,0,0,0,0,0,0,0,0,0,0,0,0};
  float m = -INFINITY, lsum = 0.0f;          // lsum is lane-local (own 32 keys)

  const int swz = (l5 & 7) ^ (l5 >> 3);      // sigma(row) for rows l5 and 32+l5

  for (int t = 0; t < NT; ++t) {
    const int cur = t & 1;
    if (t + 1 < NT) stage(cur ^ 1, kv0 + (t + 1) * KVB);

    const unsigned short* ktc = &kt[cur][0];
    const unsigned short* vtc = &vt[cur][0];

    // ---- QK^T swapped: two 32-key halves, one acc chain each --------------
    // sc[h]: row=key=32h+(r&3)+8*(r>>2)+4*b5, col=q=l5
    f32x16 sc0 = {0,0,0,0,0,0,0,0,0,0,0,0,0,0,0,0};
    f32x16 sc1 = {0,0,0,0,0,0,0,0,0,0,0,0,0,0,0,0};
    __builtin_amdgcn_s_setprio(1);
    #pragma unroll
    for (int ch = 0; ch < 4; ++ch) {
      const int P0 = ((((ch << 1) | b5) ^ swz) << 3);
      u16x8 k0 = *(const u16x8*)(ktc + l5 * 64 + P0);
      u16x8 k1 = *(const u16x8*)(ktc + (32 + l5) * 64 + P0);
      sc0 = MFMA32(k0, qh[ch], sc0);
      sc1 = MFMA32(k1, qh[ch], sc1);
    }
    __builtin_amdgcn_s_setprio(0);

    // ---- online softmax: tree max, lane-local, defer-max ------------------
    float tmx[16];
    #pragma unroll
    for (int r = 0; r < 16; ++r) tmx[r] = fmaxf(sc0[r], sc1[r]);
    #pragma unroll
    for (int r = 0; r < 8; ++r) tmx[r] = fmaxf(tmx[r], tmx[r + 8]);
    #pragma unroll
    for (int r = 0; r < 4; ++r) tmx[r] = fmaxf(tmx[r], tmx[r + 4]);
    const float smax_loc = fmaxf(fmaxf(tmx[0], tmx[1]), fmaxf(tmx[2], tmx[3]));

    if (!__all(smax_loc <= m + 8.0f)) {
      float a, bq;
      xswap32f(smax_loc, a, bq);               // uniform-per-q max
      const float mn = fmaxf(m, fmaxf(a, bq));
      const float fs = EXP2F(m - mn);          // exp2(-inf)=0 on first iter
      m = mn;
      lsum *= fs;
      #pragma unroll
      for (int r = 0; r < 16; ++r) { O0[r] *= fs; O1[r] *= fs; }
    }

    float p0[16], p1[16];
    #pragma unroll
    for (int r = 0; r < 16; ++r) {
      p0[r] = EXP2F(sc0[r] - m);
      p1[r] = EXP2F(sc1[r] - m);
    }
    {
      float u[16];
      #pragma unroll
      for (int r = 0; r < 16; ++r) u[r] = p0[r] + p1[r];
      #pragma unroll
      for (int r = 0; r < 8; ++r) u[r] += u[r + 8];
      #pragma unroll
      for (int r = 0; r < 4; ++r) u[r] += u[r + 4];
      lsum += (u[0] + u[1]) + (u[2] + u[3]);
    }

    // ---- P -> bf16 B-fragments via cvt_pk + permlane32_swap ---------------
    // frag[ks] elem j <-> key 16*ks + 8*b5 + j
    auto pack8 = [&](float a0, float a1, float a2, float a3,
                     float a4, float a5, float a6, float a7) -> u16x8 {
      unsigned int x0w = cvtpk(a0, a1), x1w = cvtpk(a2, a3);
      unsigned int y0w = cvtpk(a4, a5), y1w = cvtpk(a6, a7);
      plswap(x0w, y0w);
      plswap(x1w, y1w);
      u32x4 hw = {x0w, x1w, y0w, y1w};
      return __builtin_bit_cast(u16x8, hw);
    };
    u16x8 pb[4];
    pb[0] = pack8(p0[0], p0[1], p0[2],  p0[3],  p0[4],  p0[5],  p0[6],  p0[7]);
    pb[1] = pack8(p0[8], p0[9], p0[10], p0[11], p0[12], p0[13], p0[14], p0[15]);
    pb[2] = pack8(p1[0], p1[1], p1[2],  p1[3],  p1[4],  p1[5],  p1[6],  p1[7]);
    pb[3] = pack8(p1[8], p1[9], p1[10], p1[11], p1[12], p1[13], p1[14], p1[15]);

    // ---- PV: O^T[d][q] += V^T * P^T, two interleaved 4-chains -------------
    __builtin_amdgcn_s_setprio(1);
    #pragma unroll
    for (int ks = 0; ks < 4; ++ks) {
      const int P0 = ((((ks << 1) | b5) ^ swz) << 3);
      u16x8 v0 = *(const u16x8*)(vtc + l5 * 64 + P0);
      u16x8 v1 = *(const u16x8*)(vtc + (32 + l5) * 64 + P0);
      O0 = MFMA32(v0, pb[ks], O0);
      O1 = MFMA32(v1, pb[ks], O1);
    }
    __builtin_amdgcn_s_setprio(0);

    __syncthreads();   // drains staging vmcnt + all LDS reads of buf cur
  }

  // ---- epilogue: combine lane-local lsum across the lane^32 split ---------
  {
    float la, lb;
    xswap32f(lsum, la, lb);
    lsum = la + lb;
  }

  // ---- transpose O^T via LDS (per-wave 8KB region), write partials --------
  float* tb = (wave < 2) ? ((float*)kt + wave * 2048)
                         : ((float*)vt + (wave - 2) * 2048);
  #pragma unroll
  for (int mt = 0; mt < 2; ++mt) {
    #pragma unroll
    for (int r = 0; r < 16; ++r) {
      int d = mt * 32 + (r & 3) + ((r >> 2) << 3) + (b5 << 2);
      float val = mt ? O1[r] : O0[r];
      tb[l5 * 64 + ((((d >> 2) ^ (l5 & 15)) << 2) | (d & 3))] = val;
    }
  }
  __builtin_amdgcn_s_waitcnt(0);   // same-wave ds_write -> ds_read ordering
  #pragma unroll
  for (int L = 0; L < 8; ++L) {
    int row = L * 4 + (lane >> 4);
    int cb  = lane & 15;
    float4 val = *(const float4*)&tb[row * 64 + ((cb ^ (row & 15)) << 2)];
    long qg = (long)b * SEQ + qrow0 + row;
    *(float4*)(Opart + ((long)split * NQ + qg) * DIM + cb * 4) = val;
  }
  if (lane < 32) {
    long qg = (long)b * SEQ + qrow0 + lane;
    Mpart[(long)split * NQ + qg] = m;
    Lpart[(long)split * NQ + qg] = lsum;
  }
}

// ---------------- merge KV-split partials ----------------------------------
template<int NS>
__global__ __launch_bounds__(256) void merge_kernel(
    const float* __restrict__ Opart, const float* __restrict__ Mpart,
    const float* __restrict__ Lpart, float* __restrict__ Out) {
  int idx = blockIdx.x * 256 + threadIdx.x;  // over NQ*16
  int bq = idx >> 4;
  int d4 = (idx & 15) << 2;
  float ms[NS];
  float M = -INFINITY;
  #pragma unroll
  for (int s = 0; s < NS; ++s) { ms[s] = Mpart[s * NQ + bq]; M = fmaxf(M, ms[s]); }
  float L = 0.0f;
  float4 acc = {0, 0, 0, 0};
  #pragma unroll
  for (int s = 0; s < NS; ++s) {
    float w = EXP2F(ms[s] - M);
    L += w * Lpart[s * NQ + bq];
    float4 o = *(const float4*)(Opart + ((long)(s * NQ + bq)) * DIM + d4);
    acc.x += w * o.x; acc.y += w * o.y; acc.z += w * o.z; acc.w += w * o.w;
  }
  float inv = 1.0f / L;
  float4 r = {acc.x * inv, acc.y * inv, acc.z * inv, acc.w * inv};
  *(float4*)(Out + (long)bq * DIM + d4) = r;
}

extern "C" void kernel_launch(void* const* d_in, const int* in_sizes, int n_in,
                              void* d_out, int out_size, void* d_ws, size_t ws_size,
                              hipStream_t stream) {
  const float* Q = (const float*)d_in[0];
  const float* K = (const float*)d_in[1];
  const float* V = (const float*)d_in[2];
  float* Out = (float*)d_out;

  // ws: [Khi|VThi] bf16 (4 MB) + Opart (NS*4MB) + M/L
  unsigned short* w16  = (unsigned short*)d_ws;
  unsigned short* Khi  = w16;
  unsigned short* VThi = w16 + 1048576;
  float* wsf = (float*)(w16 + 2097152);

  const size_t need8 = (size_t)4 * 1024 * 1024 + (size_t)8 * NQ * DIM * 4
                     + (size_t)2 * 8 * NQ * 4;
  const int ns = (ws_size >= need8) ? 8 : 4;

  prep_kernel<<<dim3(256), dim3(256), 0, stream>>>(K, V, Khi, VThi);
  if (ns == 8) {
    float* Opart = wsf;
    float* Mpart = wsf + (size_t)8 * NQ * DIM;
    float* Lpart = Mpart + 8 * NQ;
    attn_kernel<8><<<dim3(1024), dim3(256), 0, stream>>>(Q, Khi, VThi, Opart, Mpart, Lpart);
    merge_kernel<8><<<dim3(1024), dim3(256), 0, stream>>>(Opart, Mpart, Lpart, Out);
  } else {
    float* Opart = wsf;
    float* Mpart = wsf + (size_t)4 * NQ * DIM;
    float* Lpart = Mpart + 4 * NQ;
    attn_kernel<4><<<dim3(512), dim3(256), 0, stream>>>(Q, Khi, VThi, Opart, Mpart, Lpart);
    merge_kernel<4><<<dim3(1024), dim3(256), 0, stream>>>(Opart, Mpart, Lpart, Out);
  }
}